// Round 1
// baseline (611.151 us; speedup 1.0000x reference)
//
#include <hip/hip_runtime.h>
#include <hip/hip_bf16.h>

typedef float f32x4 __attribute__((ext_vector_type(4)));
typedef short short8 __attribute__((ext_vector_type(8)));
typedef __hip_bfloat16 bf16;

constexpr int CDIM  = 384;
constexpr int LTOK  = 3136;      // 56*56
constexpr int NWIN  = 2048;      // 32 * 64 windows
constexpr int MROWS = 100352;    // NWIN * 49
constexpr int MPAD  = MROWS + 64;

__device__ __forceinline__ void gload_lds16(const void* g, void* l) {
  __builtin_amdgcn_global_load_lds(
      (const __attribute__((address_space(1))) void*)g,
      (__attribute__((address_space(3))) void*)l, 16, 0, 0);
}

// window-row r (w*49+n) -> (batch b, token l)
__device__ __forceinline__ void row_to_bl(int r, int& b, int& l) {
  int w = r / 49, n = r % 49;
  b = w >> 6;
  int wrem = w & 63;
  int wy = wrem >> 3, wx = wrem & 7;
  int ny = n / 7, nx = n % 7;
  l = (wy * 7 + ny) * 56 + wx * 7 + nx;
}

// ---------------- tiny prep kernels ----------------

__global__ __launch_bounds__(256) void mod_kernel(
    const float* __restrict__ cond, const float* __restrict__ mw,
    const float* __restrict__ mb, float* __restrict__ mod) {
  int idx = blockIdx.x * 256 + threadIdx.x;   // 32*768 = 24576 exact
  int b = idx / 768, j = idx % 768;
  float s = mb[j];
  const float* cr = cond + b * 128;
  #pragma unroll 4
  for (int k = 0; k < 128; k++) s += cr[k] * mw[(size_t)k * 768 + j];
  mod[idx] = s;
}

__global__ __launch_bounds__(256) void prep_wt(
    const float* __restrict__ qw, const float* __restrict__ kvw,
    const float* __restrict__ pw,
    bf16* __restrict__ wtq, bf16* __restrict__ wtkv, bf16* __restrict__ wtp) {
  int idx = blockIdx.x * 256 + threadIdx.x;   // 589824 exact
  if (idx < 147456) {
    int n = idx / 384, k = idx % 384;
    wtq[idx] = __float2bfloat16(qw[(size_t)k * 384 + n]);
  } else if (idx < 147456 + 294912) {
    int i = idx - 147456;
    int n = i / 384, k = i % 384;
    wtkv[i] = __float2bfloat16(kvw[(size_t)k * 768 + n]);
  } else {
    int i = idx - 442368;
    int n = i / 384, k = i % 384;
    wtp[i] = __float2bfloat16(pw[(size_t)k * 384 + n]);
  }
}

// biasT[h][m][c], m = q row (0..63), c = k col (0..63); -1e30 masks padded cols
__global__ __launch_bounds__(256) void bias_kernel(
    const float* __restrict__ tab, float* __restrict__ bT) {
  int idx = blockIdx.x * 256 + threadIdx.x;   // 12*64*64 = 49152 exact
  int h = idx >> 12, rem = idx & 4095, m = rem >> 6, c = rem & 63;
  float v;
  if (c >= 49)      v = -1e30f;
  else if (m >= 49) v = 0.f;
  else {
    int yq = m / 7, xq = m % 7, yk = c / 7, xk = c % 7;
    v = tab[((yq - yk + 6) * 13 + (xq - xk + 6)) * 12 + h];
  }
  bT[idx] = v;
}

// ---------------- LayerNorm (+optional AdaLN modulation), window-permuted bf16 out ----------------

__global__ __launch_bounds__(256) void ln_kernel(
    const float* __restrict__ src, const float* __restrict__ gamma,
    const float* __restrict__ beta, const float* __restrict__ mod,
    float eps, bf16* __restrict__ dst) {
  int wid = threadIdx.x >> 6, lane = threadIdx.x & 63;
  int r = blockIdx.x * 4 + wid;               // window-row, 25088*4 = 100352 exact
  int bb, ll; row_to_bl(r, bb, ll);
  const float* x = src + ((size_t)bb * LTOK + ll) * 384;
  float v[6]; float s = 0.f, s2 = 0.f;
  #pragma unroll
  for (int i = 0; i < 6; i++) {
    v[i] = x[lane + 64 * i];
    s += v[i]; s2 += v[i] * v[i];
  }
  #pragma unroll
  for (int d = 1; d < 64; d <<= 1) { s += __shfl_xor(s, d); s2 += __shfl_xor(s2, d); }
  float mu = s * (1.f / 384.f);
  float var = s2 * (1.f / 384.f) - mu * mu;
  float rstd = rsqrtf(var + eps);
  bf16* o = dst + (size_t)r * 384;
  if (mod != nullptr) {
    const float* mg = mod + bb * 768;
    #pragma unroll
    for (int i = 0; i < 6; i++) {
      int c = lane + 64 * i;
      float y = (gamma[c] * (1.f + mg[c])) * ((v[i] - mu) * rstd) + beta[c] + mg[384 + c];
      o[c] = __float2bfloat16(y);
    }
  } else {
    #pragma unroll
    for (int i = 0; i < 6; i++) {
      int c = lane + 64 * i;
      o[c] = __float2bfloat16((v[i] - mu) * rstd * gamma[c] + beta[c]);
    }
  }
}

// ---------------- 128x128 tile bf16 GEMM, K=384, MODE 0: bf16 (acc+bias)*scale, MODE 1: f32 resid+unpermute ----------------

template<int MODE>
__global__ __launch_bounds__(256) void gemm_kernel(
    const bf16* __restrict__ A, const bf16* __restrict__ WT,
    const float* __restrict__ bias, void* __restrict__ outp,
    const float* __restrict__ resid, float scale, int N) {
  __shared__ __align__(16) bf16 As[128 * 64];
  __shared__ __align__(16) bf16 Bs[128 * 64];
  const int bm = blockIdx.x * 128;
  const int bn = blockIdx.y * 128;
  const int t = threadIdx.x;
  const int wid = t >> 6, lane = t & 63;
  const int r16 = lane & 15, g = lane >> 4;
  const int wr = wid >> 1, wc = wid & 1;

  f32x4 acc[4][4] = {};

  for (int k0 = 0; k0 < 384; k0 += 64) {
    if (k0) __syncthreads();
    #pragma unroll
    for (int i = 0; i < 4; i++) {
      int c = wid * 256 + i * 64 + lane;
      int row = c >> 3, col8 = (c & 7) << 3;
      gload_lds16(A + (size_t)(bm + row) * 384 + k0 + col8,
                  (char*)As + (size_t)(wid * 256 + i * 64) * 16);
    }
    #pragma unroll
    for (int i = 0; i < 4; i++) {
      int c = wid * 256 + i * 64 + lane;
      int row = c >> 3, col8 = (c & 7) << 3;
      gload_lds16(WT + (size_t)(bn + row) * 384 + k0 + col8,
                  (char*)Bs + (size_t)(wid * 256 + i * 64) * 16);
    }
    __syncthreads();
    #pragma unroll
    for (int kk = 0; kk < 2; kk++) {
      short8 a[4], b[4];
      #pragma unroll
      for (int m = 0; m < 4; m++)
        a[m] = *(const short8*)((const char*)As + (wr * 64 + m * 16 + r16) * 128 + kk * 64 + g * 16);
      #pragma unroll
      for (int n = 0; n < 4; n++)
        b[n] = *(const short8*)((const char*)Bs + (wc * 64 + n * 16 + r16) * 128 + kk * 64 + g * 16);
      #pragma unroll
      for (int m = 0; m < 4; m++)
        #pragma unroll
        for (int n = 0; n < 4; n++)
          acc[m][n] = __builtin_amdgcn_mfma_f32_16x16x32_bf16(a[m], b[n], acc[m][n], 0, 0, 0);
    }
  }

  if (MODE == 0) {
    bf16* O = (bf16*)outp;
    #pragma unroll
    for (int n = 0; n < 4; n++) {
      int col = bn + wc * 64 + n * 16 + r16;
      float bc = bias[col];
      #pragma unroll
      for (int m = 0; m < 4; m++) {
        int row0 = bm + wr * 64 + m * 16 + g * 4;
        #pragma unroll
        for (int r = 0; r < 4; r++) {
          float v = (acc[m][n][r] + bc) * scale;
          O[(size_t)(row0 + r) * N + col] = __float2bfloat16(v);
        }
      }
    }
  } else {
    float* O = (float*)outp;
    #pragma unroll
    for (int m = 0; m < 4; m++) {
      #pragma unroll
      for (int r = 0; r < 4; r++) {
        int row = bm + wr * 64 + m * 16 + g * 4 + r;
        int bb, ll; row_to_bl(row, bb, ll);
        size_t base = ((size_t)bb * LTOK + ll) * 384;
        #pragma unroll
        for (int n = 0; n < 4; n++) {
          int col = bn + wc * 64 + n * 16 + r16;
          O[base + col] = resid[base + col] + acc[m][n][r] + bias[col];
        }
      }
    }
  }
}

// ---------------- attention: one wave per (window, head) ----------------

__global__ __launch_bounds__(64) void attn_kernel(
    const bf16* __restrict__ q, const bf16* __restrict__ kv,
    const float* __restrict__ biasT, bf16* __restrict__ o) {
  __shared__ __align__(16) bf16 vt[32][72];   // V^T, padded
  __shared__ __align__(16) bf16 P[64][72];    // probs, padded
  const int h = blockIdx.x, w = blockIdx.y;
  const int lane = threadIdx.x;
  const int r16 = lane & 15, g = lane >> 4;
  const size_t qbase = (size_t)w * 49 * 384 + h * 32;
  const size_t kvbase = (size_t)w * 49 * 768 + h * 32;

  // zero vt (pad cols must be 0, LDS is uninitialized), then fill V^T
  for (int e = lane; e < 32 * 72; e += 64) ((bf16*)vt)[e] = __float2bfloat16(0.f);
  for (int e = lane; e < 49 * 32; e += 64) {
    int c = e >> 5, d = e & 31;
    vt[d][c] = kv[kvbase + (size_t)c * 768 + 384 + d];
  }

  // QK^T: A and B fragments straight from global (both k-contiguous)
  short8 aq[4], bk[4];
  #pragma unroll
  for (int mi = 0; mi < 4; mi++)
    aq[mi] = *(const short8*)(q + qbase + (size_t)(mi * 16 + r16) * 384 + g * 8);
  #pragma unroll
  for (int ni = 0; ni < 4; ni++)
    bk[ni] = *(const short8*)(kv + kvbase + (size_t)(ni * 16 + r16) * 768 + g * 8);

  f32x4 zero = {0.f, 0.f, 0.f, 0.f};
  f32x4 S[4][4];
  #pragma unroll
  for (int mi = 0; mi < 4; mi++)
    #pragma unroll
    for (int ni = 0; ni < 4; ni++)
      S[mi][ni] = __builtin_amdgcn_mfma_f32_16x16x32_bf16(aq[mi], bk[ni], zero, 0, 0, 0);

  // bias + softmax (rows split over 16-lane groups; cols>=49 get -1e30 from biasT)
  const float* bt = biasT + h * 4096;
  #pragma unroll
  for (int mi = 0; mi < 4; mi++) {
    #pragma unroll
    for (int r = 0; r < 4; r++) {
      int rowm = mi * 16 + g * 4 + r;
      float sv[4];
      #pragma unroll
      for (int ni = 0; ni < 4; ni++)
        sv[ni] = S[mi][ni][r] + bt[rowm * 64 + ni * 16 + r16];
      float mx = fmaxf(fmaxf(sv[0], sv[1]), fmaxf(sv[2], sv[3]));
      #pragma unroll
      for (int d = 1; d < 16; d <<= 1) mx = fmaxf(mx, __shfl_xor(mx, d));
      float sum = 0.f;
      #pragma unroll
      for (int ni = 0; ni < 4; ni++) { sv[ni] = __expf(sv[ni] - mx); sum += sv[ni]; }
      #pragma unroll
      for (int d = 1; d < 16; d <<= 1) sum += __shfl_xor(sum, d);
      float inv = __fdividef(1.f, sum);
      #pragma unroll
      for (int ni = 0; ni < 4; ni++)
        P[rowm][ni * 16 + r16] = __float2bfloat16(sv[ni] * inv);
    }
  }
  __syncthreads();

  // PV
  f32x4 acc[4][2] = {};
  #pragma unroll
  for (int c0 = 0; c0 < 2; c0++) {
    short8 ap[4], bv[2];
    #pragma unroll
    for (int mi = 0; mi < 4; mi++)
      ap[mi] = *(const short8*)((const char*)&P[0][0] + (mi * 16 + r16) * 144 + c0 * 64 + g * 16);
    #pragma unroll
    for (int di = 0; di < 2; di++)
      bv[di] = *(const short8*)((const char*)&vt[0][0] + (di * 16 + r16) * 144 + c0 * 64 + g * 16);
    #pragma unroll
    for (int mi = 0; mi < 4; mi++)
      #pragma unroll
      for (int di = 0; di < 2; di++)
        acc[mi][di] = __builtin_amdgcn_mfma_f32_16x16x32_bf16(ap[mi], bv[di], acc[mi][di], 0, 0, 0);
  }

  #pragma unroll
  for (int mi = 0; mi < 4; mi++) {
    #pragma unroll
    for (int r = 0; r < 4; r++) {
      int m = mi * 16 + g * 4 + r;
      if (m < 49) {
        #pragma unroll
        for (int di = 0; di < 2; di++)
          o[(size_t)(w * 49 + m) * 384 + h * 32 + di * 16 + r16] =
              __float2bfloat16(acc[mi][di][r]);
      }
    }
  }
}

// ---------------- launch ----------------

extern "C" void kernel_launch(void* const* d_in, const int* in_sizes, int n_in,
                              void* d_out, int out_size, void* d_ws, size_t ws_size,
                              hipStream_t stream) {
  (void)in_sizes; (void)n_in; (void)out_size; (void)ws_size;
  const float* x_tok   = (const float*)d_in[0];
  const float* z_tok   = (const float*)d_in[1];
  const float* cond    = (const float*)d_in[2];
  const float* gamma_x = (const float*)d_in[3];
  const float* beta_x  = (const float*)d_in[4];
  const float* mod_w   = (const float*)d_in[5];
  const float* mod_b   = (const float*)d_in[6];
  const float* gamma_z = (const float*)d_in[7];
  const float* beta_z  = (const float*)d_in[8];
  const float* rel_tab = (const float*)d_in[9];
  const float* q_b     = (const float*)d_in[11];
  const float* kv_b    = (const float*)d_in[13];
  const float* proj_b  = (const float*)d_in[15];
  const float* q_w     = (const float*)d_in[10];
  const float* kv_w    = (const float*)d_in[12];
  const float* proj_w  = (const float*)d_in[14];

  char* ws = (char*)d_ws;
  float* modbuf = (float*)(ws + 0);                          //  98304 B
  bf16*  wtq    = (bf16*)(ws + 98304);                       // 294912 B  [384][384]
  bf16*  wtkv   = (bf16*)(ws + 98304 + 294912);              // 589824 B  [768][384]
  bf16*  wtp    = (bf16*)(ws + 98304 + 294912 + 589824);     // 294912 B  [384][384]
  float* biasT  = (float*)(ws + 98304 + 294912 + 589824 + 294912); // 196608 B
  char*  R1     = ws + 1474560;                              // MPAD*384*2 (x_ln / z_ln / attn_out)
  char*  R2     = R1 + (size_t)MPAD * 384 * 2;               // q
  char*  R3     = R2 + (size_t)MPAD * 384 * 2;               // kv  (MPAD*768*2)
  // peak ws use ~310 MB

  // zero pad rows (attention fragment loads read past the last window)
  hipMemsetAsync(R2 + (size_t)MROWS * 384 * 2, 0, 64 * 384 * 2, stream);
  hipMemsetAsync(R3 + (size_t)MROWS * 768 * 2, 0, 64 * 768 * 2, stream);

  mod_kernel <<<96,   256, 0, stream>>>(cond, mod_w, mod_b, modbuf);
  prep_wt    <<<2304, 256, 0, stream>>>(q_w, kv_w, proj_w, wtq, wtkv, wtp);
  bias_kernel<<<192,  256, 0, stream>>>(rel_tab, biasT);

  ln_kernel<<<25088, 256, 0, stream>>>(x_tok, gamma_x, beta_x, modbuf, 1e-6f, (bf16*)R1);
  gemm_kernel<0><<<dim3(784, 3), 256, 0, stream>>>(
      (const bf16*)R1, wtq, q_b, R2, nullptr, 0.17677669529663687f, 384);
  ln_kernel<<<25088, 256, 0, stream>>>(z_tok, gamma_z, beta_z, nullptr, 1e-5f, (bf16*)R1);
  gemm_kernel<0><<<dim3(784, 6), 256, 0, stream>>>(
      (const bf16*)R1, wtkv, kv_b, R3, nullptr, 1.0f, 768);
  attn_kernel<<<dim3(12, NWIN), 64, 0, stream>>>(
      (const bf16*)R2, (const bf16*)R3, biasT, (bf16*)R1);
  gemm_kernel<1><<<dim3(784, 3), 256, 0, stream>>>(
      (const bf16*)R1, wtp, proj_b, d_out, x_tok, 1.0f, 384);
}